// Round 3
// baseline (587.195 us; speedup 1.0000x reference)
//
#include <hip/hip_runtime.h>
#include <hip/hip_bf16.h>
#include <math.h>

#define D 1024
#define NTOK 8192
#define NSLOT 16384
#define NGRP 64
#define MAXTILE 136

typedef short bf16x8 __attribute__((ext_vector_type(8)));
typedef float floatx4 __attribute__((ext_vector_type(4)));

__device__ __forceinline__ unsigned short f2bf(float f) {
    __hip_bfloat16 h = __float2bfloat16(f);
    return *reinterpret_cast<unsigned short*>(&h);
}
__device__ __forceinline__ float bf2f(unsigned short u) {
    unsigned int v = ((unsigned int)u) << 16;
    return __uint_as_float(v);
}

__device__ __forceinline__ void load_lds16(const void* g, void* l) {
    __builtin_amdgcn_global_load_lds(
        (const __attribute__((address_space(1))) unsigned int*)g,
        (__attribute__((address_space(3))) unsigned int*)l, 16, 0, 0);
}

// ---------- zero scratch ----------
__global__ void zero_kernel(int* __restrict__ grp_cnt, float* __restrict__ S) {
    int i = blockIdx.x * 256 + threadIdx.x;
    if (i < NGRP) grp_cnt[i] = 0;
    if (i < 64 * D) S[i] = 0.f;
}

// ---------- routing: logits + top-2 ----------
__global__ void route_kernel(const float* __restrict__ x, const float* __restrict__ Wg,
                             const float* __restrict__ bg, int* __restrict__ slot_e,
                             int* __restrict__ grp_cnt) {
    int wave = threadIdx.x >> 6;
    int lane = threadIdx.x & 63;
    int tok = blockIdx.x * 4 + wave;
    const float* xr = x + (size_t)tok * D;
    float acc[8] = {0.f,0.f,0.f,0.f,0.f,0.f,0.f,0.f};
    for (int k = lane; k < D; k += 64) {
        float xv = xr[k];
        const float4* w4 = reinterpret_cast<const float4*>(Wg + k * 8);
        float4 a = w4[0], b = w4[1];
        acc[0] += xv * a.x; acc[1] += xv * a.y; acc[2] += xv * a.z; acc[3] += xv * a.w;
        acc[4] += xv * b.x; acc[5] += xv * b.y; acc[6] += xv * b.z; acc[7] += xv * b.w;
    }
#pragma unroll
    for (int e = 0; e < 8; e++) {
#pragma unroll
        for (int off = 32; off > 0; off >>= 1)
            acc[e] += __shfl_xor(acc[e], off, 64);
    }
    if (lane == 0) {
        float lg[8];
#pragma unroll
        for (int e = 0; e < 8; e++) lg[e] = acc[e] + bg[e];
        int e1 = 0; float b1v = lg[0];
#pragma unroll
        for (int e = 1; e < 8; e++) if (lg[e] > b1v) { b1v = lg[e]; e1 = e; }
        int e2 = -1; float b2v = -3.0e38f;
#pragma unroll
        for (int e = 0; e < 8; e++) { if (e == e1) continue; if (lg[e] > b2v) { b2v = lg[e]; e2 = e; } }
        int b = tok >> 10;
        slot_e[2 * tok] = e1;
        slot_e[2 * tok + 1] = e2;
        atomicAdd(&grp_cnt[e1 * 8 + b], 1);
        atomicAdd(&grp_cnt[e2 * 8 + b], 1);
    }
}

// ---------- prefix sum + tile table ----------
__global__ void prefix_kernel(const int* __restrict__ grp_cnt, int* __restrict__ goff,
                              int* __restrict__ cursor, int2* __restrict__ tile_tab) {
    if (threadIdx.x != 0) return;
    int s = 0;
    for (int g = 0; g < NGRP; g++) { goff[g] = s; cursor[g] = s; s += grp_cnt[g]; }
    goff[NGRP] = s;
    int t = 0;
    for (int e = 0; e < 8; e++) {
        int cnt = goff[e * 8 + 8] - goff[e * 8];
        for (int m0 = 0; m0 < cnt; m0 += 128) tile_tab[t++] = make_int2(e, m0);
    }
    for (; t < MAXTILE; t++) tile_tab[t] = make_int2(-1, 0);
}

// ---------- gather x + noise into grouped bf16 rows ----------
__global__ void build_xg_kernel(const float* __restrict__ x, const float* __restrict__ noise,
                                const int* __restrict__ slot_e, int* __restrict__ cursor,
                                unsigned short* __restrict__ xg) {
    int wave = threadIdx.x >> 6;
    int lane = threadIdx.x & 63;
    int slot = blockIdx.x * 4 + wave;
    int e = slot_e[slot];
    int b = slot >> 11;
    int row = 0;
    if (lane == 0) row = atomicAdd(&cursor[e * 8 + b], 1);
    row = __shfl(row, 0, 64);
    int tok = slot >> 1;
    const float4* xr = reinterpret_cast<const float4*>(x + (size_t)tok * D);
    const float4* nr = reinterpret_cast<const float4*>(noise + (size_t)slot * D);
    ushort4* og = reinterpret_cast<ushort4*>(xg + (size_t)row * D);
    for (int i = lane; i < D / 4; i += 64) {
        float4 a = xr[i], n = nr[i];
        ushort4 o;
        o.x = f2bf(a.x + n.x); o.y = f2bf(a.y + n.y);
        o.z = f2bf(a.z + n.z); o.w = f2bf(a.w + n.w);
        og[i] = o;
    }
}

// ---------- W fp32 [e][k][n] -> bf16 blocked [e][k/8][n][8], no LDS ----------
__global__ void wconv_kernel(const float* __restrict__ W1, const float* __restrict__ W2,
                             unsigned short* __restrict__ W1t, unsigned short* __restrict__ W2t) {
    int z = blockIdx.y;            // e*2 + mat
    int mat = z & 1, e = z >> 1;
    const float* src = (mat ? W2 : W1) + (size_t)e * D * D;
    unsigned short* dst = (mat ? W2t : W1t) + (size_t)e * D * D;
    int kc = blockIdx.x;           // 16 chunks of 64 k-rows
    int tid = threadIdx.x;
#pragma unroll
    for (int p = 0; p < 4; p++) {
        int n = p * 256 + tid;
#pragma unroll
        for (int kb = 0; kb < 8; kb++) {
            int kbase = kc * 64 + kb * 8;
            unsigned int w[4];
#pragma unroll
            for (int kk = 0; kk < 4; kk++) {
                unsigned short lo = f2bf(src[(size_t)(kbase + 2 * kk) * D + n]);
                unsigned short hi = f2bf(src[(size_t)(kbase + 2 * kk + 1) * D + n]);
                w[kk] = (unsigned int)lo | ((unsigned int)hi << 16);
            }
            uint4 o = make_uint4(w[0], w[1], w[2], w[3]);
            *reinterpret_cast<uint4*>(dst + (size_t)(kbase >> 3) * (D * 8) + (size_t)n * 8) = o;
        }
    }
}

// ---------- grouped GEMM: 128x64 tile, dbuf LDS, global_load_lds ----------
// A: row-major bf16 [m][1024].  Wt: blocked bf16 [e][k/8][n][8].
// MODE 0: H = gelu(A @ W^T + b1)   MODE 1: Y = A @ W^T + b2 + xg
template <int MODE>
__global__ __launch_bounds__(256)
void gemm_kernel(const unsigned short* __restrict__ A,
                 const unsigned short* __restrict__ Wt,
                 const float* __restrict__ bias,
                 const unsigned short* __restrict__ xg,
                 const int2* __restrict__ tile_tab,
                 const int* __restrict__ goff,
                 unsigned short* __restrict__ Hout) {
    __shared__ unsigned short As[2][128 * 32];   // 2 x 8 KB
    __shared__ unsigned short Bs[2][64 * 32];    // 2 x 4 KB

    int2 tt = tile_tab[blockIdx.y];
    int e = tt.x;
    if (e < 0) return;
    int m0 = tt.y;
    int rowBase = goff[e * 8];
    int cnt = goff[e * 8 + 8] - rowBase;
    int n0 = blockIdx.x * 64;

    int tid = threadIdx.x;
    int lane = tid & 63, wave = tid >> 6;
    int wm = wave >> 1, wn = wave & 1;
    int lr = lane & 15, quad = lane >> 4;
    int l2 = lane >> 2, l4 = lane & 3;

    // K-invariant staging addresses (advance by constant per stage)
    int arow0 = min(m0 + (wave * 2 + 0) * 16 + l2, cnt - 1);
    int arow1 = min(m0 + (wave * 2 + 1) * 16 + l2, cnt - 1);
    const unsigned short* ap0 = A + ((size_t)(rowBase + arow0) << 10) + l4 * 8;
    const unsigned short* ap1 = A + ((size_t)(rowBase + arow1) << 10) + l4 * 8;
    const unsigned short* bp = Wt + (size_t)e * D * D
                               + (size_t)l4 * (D * 8)
                               + (size_t)(n0 + wave * 16 + l2) * 8;

    unsigned short* a_dst0[2] = { &As[0][(wave * 2 + 0) * 512 + lane * 8],
                                  &As[1][(wave * 2 + 0) * 512 + lane * 8] };
    unsigned short* a_dst1[2] = { &As[0][(wave * 2 + 1) * 512 + lane * 8],
                                  &As[1][(wave * 2 + 1) * 512 + lane * 8] };
    unsigned short* b_dst[2]  = { &Bs[0][wave * 512 + lane * 8],
                                  &Bs[1][wave * 512 + lane * 8] };

    const unsigned short* a_frag = &As[0][(wm * 64 + lr) * 32 + quad * 8];
    const unsigned short* b_frag = &Bs[0][(wn * 32 + lr) * 32 + quad * 8];

    floatx4 acc[4][2] = {};

    // stage k=0 into buf 0
    load_lds16(ap0, a_dst0[0]); load_lds16(ap1, a_dst1[0]); load_lds16(bp, b_dst[0]);
    ap0 += 32; ap1 += 32; bp += 4 * D * 8;

#pragma unroll 1
    for (int k0 = 0; k0 < D; k0 += 64) {
        __syncthreads();                                   // buf0 (k0) ready
        if (k0 + 32 < D) {                                 // stage k0+32 -> buf1
            load_lds16(ap0, a_dst0[1]); load_lds16(ap1, a_dst1[1]); load_lds16(bp, b_dst[1]);
            ap0 += 32; ap1 += 32; bp += 4 * D * 8;
        }
        {   // compute buf0
            bf16x8 af[4], bfr[2];
#pragma unroll
            for (int i = 0; i < 4; i++)
                af[i] = *reinterpret_cast<const bf16x8*>(a_frag + i * 512);
#pragma unroll
            for (int j = 0; j < 2; j++)
                bfr[j] = *reinterpret_cast<const bf16x8*>(b_frag + j * 512);
#pragma unroll
            for (int i = 0; i < 4; i++)
#pragma unroll
                for (int j = 0; j < 2; j++)
                    acc[i][j] = __builtin_amdgcn_mfma_f32_16x16x32_bf16(af[i], bfr[j], acc[i][j], 0, 0, 0);
        }
        __syncthreads();                                   // buf1 (k0+32) ready
        if (k0 + 64 < D) {                                 // stage k0+64 -> buf0
            load_lds16(ap0, a_dst0[0]); load_lds16(ap1, a_dst1[0]); load_lds16(bp, b_dst[0]);
            ap0 += 32; ap1 += 32; bp += 4 * D * 8;
        }
        {   // compute buf1
            bf16x8 af[4], bfr[2];
#pragma unroll
            for (int i = 0; i < 4; i++)
                af[i] = *reinterpret_cast<const bf16x8*>(a_frag + 4096 + i * 512);
#pragma unroll
            for (int j = 0; j < 2; j++)
                bfr[j] = *reinterpret_cast<const bf16x8*>(b_frag + 2048 + j * 512);
#pragma unroll
            for (int i = 0; i < 4; i++)
#pragma unroll
                for (int j = 0; j < 2; j++)
                    acc[i][j] = __builtin_amdgcn_mfma_f32_16x16x32_bf16(af[i], bfr[j], acc[i][j], 0, 0, 0);
        }
    }

#pragma unroll
    for (int i = 0; i < 4; i++) {
        int rowb = m0 + wm * 64 + i * 16 + quad * 4;
#pragma unroll
        for (int j = 0; j < 2; j++) {
            int col = n0 + wn * 32 + j * 16 + lr;
            float bia = bias[e * D + col];
#pragma unroll
            for (int r = 0; r < 4; r++) {
                int rr = rowb + r;
                if (rr < cnt) {
                    float v = acc[i][j][r] + bia;
                    size_t idx = (size_t)(rowBase + rr) * D + col;
                    if (MODE == 0) {
                        float g = 0.5f * v * (1.0f + erff(v * 0.70710678118654752f));
                        Hout[idx] = f2bf(g);
                    } else {
                        v += bf2f(xg[idx]);
                        Hout[idx] = f2bf(v);
                    }
                }
            }
        }
    }
}

// ---------- fused per-row LN + per-(e,b) segment sum (wave per row) ----------
__global__ void lnsum_kernel(const unsigned short* __restrict__ ybf,
                             const int* __restrict__ goff, float* __restrict__ S) {
    int grp = blockIdx.x, chunk = blockIdx.y;
    int r0 = goff[grp] + chunk * 64;
    int r1 = min(goff[grp + 1], r0 + 64);
    if (r0 >= r1) return;
    __shared__ float part[D];
    for (int i = threadIdx.x; i < D; i += 256) part[i] = 0.f;
    __syncthreads();

    int wave = threadIdx.x >> 6, lane = threadIdx.x & 63;
    float p[16] = {0.f};
    for (int r = r0 + wave; r < r1; r += 4) {
        const unsigned short* row = ybf + ((size_t)r << 10);
        float v[16];
        float s = 0.f, sq = 0.f;
#pragma unroll
        for (int c = 0; c < 4; c++) {
            ushort4 u = *reinterpret_cast<const ushort4*>(row + c * 256 + lane * 4);
            float a = bf2f(u.x), b = bf2f(u.y), cc = bf2f(u.z), d = bf2f(u.w);
            v[c * 4 + 0] = a; v[c * 4 + 1] = b; v[c * 4 + 2] = cc; v[c * 4 + 3] = d;
            s += a + b + cc + d;
            sq += a * a + b * b + cc * cc + d * d;
        }
#pragma unroll
        for (int off = 32; off > 0; off >>= 1) {
            s += __shfl_xor(s, off, 64);
            sq += __shfl_xor(sq, off, 64);
        }
        float m = s * (1.f / 1024.f);
        float rs = rsqrtf(sq * (1.f / 1024.f) - m * m + 1e-5f);
#pragma unroll
        for (int c = 0; c < 16; c++) p[c] += (v[c] - m) * rs;
    }
#pragma unroll
    for (int c = 0; c < 4; c++)
#pragma unroll
        for (int q = 0; q < 4; q++)
            atomicAdd(&part[c * 256 + lane * 4 + q], p[c * 4 + q]);
    __syncthreads();

    int e = grp >> 3, b = grp & 7;
    float* Sp = S + (size_t)(b * 8 + e) * D;
    for (int i = threadIdx.x; i < D; i += 256)
        atomicAdd(&Sp[i], part[i]);
}

// ---------- finalize: ln scale/bias + final group LN ----------
__global__ void finalize_kernel(const float* __restrict__ S, const int* __restrict__ goff,
                                const float* __restrict__ ln_g, const float* __restrict__ ln_b,
                                const float* __restrict__ gn_g, const float* __restrict__ gn_b,
                                float* __restrict__ out) {
    int be = blockIdx.x;           // b*8 + e
    int b = be >> 3, e = be & 7;
    int grp = e * 8 + b;
    float cnt = (float)(goff[grp + 1] - goff[grp]);
    int tid = threadIdx.x;
    __shared__ float red[8];
    float val[4];
    float s = 0.f, sq = 0.f;
#pragma unroll
    for (int c = 0; c < 4; c++) {
        int d = tid * 4 + c;
        float v = S[(size_t)be * D + d] * ln_g[e * D + d] + cnt * ln_b[e * D + d];
        val[c] = v; s += v; sq += v * v;
    }
#pragma unroll
    for (int off = 32; off > 0; off >>= 1) {
        s += __shfl_xor(s, off, 64);
        sq += __shfl_xor(sq, off, 64);
    }
    int wave = tid >> 6, lane = tid & 63;
    if (lane == 0) { red[wave] = s; red[4 + wave] = sq; }
    __syncthreads();
    float ts = red[0] + red[1] + red[2] + red[3];
    float tq = red[4] + red[5] + red[6] + red[7];
    float m = ts / 1024.f;
    float var = tq / 1024.f - m * m;
    float rstd = rsqrtf(var + 1e-5f);
#pragma unroll
    for (int c = 0; c < 4; c++) {
        int d = tid * 4 + c;
        out[(size_t)be * D + d] = (val[c] - m) * rstd * gn_g[d] + gn_b[d];
    }
}

extern "C" void kernel_launch(void* const* d_in, const int* in_sizes, int n_in,
                              void* d_out, int out_size, void* d_ws, size_t ws_size,
                              hipStream_t stream) {
    const float* x     = (const float*)d_in[0];
    const float* noise = (const float*)d_in[1];
    const float* Wg    = (const float*)d_in[2];
    const float* bg    = (const float*)d_in[3];
    const float* W1    = (const float*)d_in[4];
    const float* b1    = (const float*)d_in[5];
    const float* W2    = (const float*)d_in[6];
    const float* b2    = (const float*)d_in[7];
    const float* ln_g  = (const float*)d_in[8];
    const float* ln_b  = (const float*)d_in[9];
    const float* gn_g  = (const float*)d_in[10];
    const float* gn_b  = (const float*)d_in[11];
    float* out = (float*)d_out;

    char* ws = (char*)d_ws;
    size_t off = 0;
    unsigned short* xg   = (unsigned short*)(ws + off); off += (size_t)NSLOT * D * 2;   // 32 MB
    unsigned short* hb   = (unsigned short*)(ws + off); off += (size_t)NSLOT * D * 2;   // 32 MB
    unsigned short* ybf  = (unsigned short*)(ws + off); off += (size_t)NSLOT * D * 2;   // 32 MB
    unsigned short* W1t  = (unsigned short*)(ws + off); off += (size_t)8 * D * D * 2;   // 16 MB
    unsigned short* W2t  = (unsigned short*)(ws + off); off += (size_t)8 * D * D * 2;   // 16 MB
    int* slot_e          = (int*)(ws + off);            off += (size_t)NSLOT * 4;
    int* grp_cnt         = (int*)(ws + off);            off += 256;
    int* goff            = (int*)(ws + off);            off += 512;
    int* cursor          = (int*)(ws + off);            off += 256;
    int2* tile_tab       = (int2*)(ws + off);           off += MAXTILE * 8;
    float* S             = (float*)(ws + off);          off += (size_t)64 * D * 4;

    zero_kernel<<<256, 256, 0, stream>>>(grp_cnt, S);
    route_kernel<<<NTOK / 4, 256, 0, stream>>>(x, Wg, bg, slot_e, grp_cnt);
    prefix_kernel<<<1, 64, 0, stream>>>(grp_cnt, goff, cursor, tile_tab);
    wconv_kernel<<<dim3(16, 16), 256, 0, stream>>>(W1, W2, W1t, W2t);
    build_xg_kernel<<<NSLOT / 4, 256, 0, stream>>>(x, noise, slot_e, cursor, xg);
    gemm_kernel<0><<<dim3(16, MAXTILE), 256, 0, stream>>>(xg, W1t, b1, xg, tile_tab, goff, hb);
    gemm_kernel<1><<<dim3(16, MAXTILE), 256, 0, stream>>>(hb, W2t, b2, xg, tile_tab, goff, ybf);
    lnsum_kernel<<<dim3(64, 16), 256, 0, stream>>>(ybf, goff, S);
    finalize_kernel<<<64, 256, 0, stream>>>(S, goff, ln_g, ln_b, gn_g, gn_b, out);
}

// Round 4
// 538.557 us; speedup vs baseline: 1.0903x; 1.0903x over previous
//
#include <hip/hip_runtime.h>
#include <hip/hip_bf16.h>
#include <math.h>

#define D 1024
#define NTOK 8192
#define NSLOT 16384
#define NGRP 64
#define MAXTILE 136

typedef short bf16x8 __attribute__((ext_vector_type(8)));
typedef float floatx4 __attribute__((ext_vector_type(4)));

__device__ __forceinline__ unsigned short f2bf(float f) {
    __hip_bfloat16 h = __float2bfloat16(f);
    return *reinterpret_cast<unsigned short*>(&h);
}
__device__ __forceinline__ float bf2f(unsigned short u) {
    unsigned int v = ((unsigned int)u) << 16;
    return __uint_as_float(v);
}

__device__ __forceinline__ void load_lds16(const void* g, void* l) {
    __builtin_amdgcn_global_load_lds(
        (const __attribute__((address_space(1))) unsigned int*)g,
        (__attribute__((address_space(3))) unsigned int*)l, 16, 0, 0);
}

// ---------- zero scratch ----------
__global__ void zero_kernel(int* __restrict__ grp_cnt, float* __restrict__ S) {
    int i = blockIdx.x * 256 + threadIdx.x;
    if (i < NGRP) grp_cnt[i] = 0;
    if (i < 64 * D) S[i] = 0.f;
}

// ---------- routing: logits + top-2 ----------
__global__ void route_kernel(const float* __restrict__ x, const float* __restrict__ Wg,
                             const float* __restrict__ bg, int* __restrict__ slot_e,
                             int* __restrict__ grp_cnt) {
    int wave = threadIdx.x >> 6;
    int lane = threadIdx.x & 63;
    int tok = blockIdx.x * 4 + wave;
    const float* xr = x + (size_t)tok * D;
    float acc[8] = {0.f,0.f,0.f,0.f,0.f,0.f,0.f,0.f};
    for (int k = lane; k < D; k += 64) {
        float xv = xr[k];
        const float4* w4 = reinterpret_cast<const float4*>(Wg + k * 8);
        float4 a = w4[0], b = w4[1];
        acc[0] += xv * a.x; acc[1] += xv * a.y; acc[2] += xv * a.z; acc[3] += xv * a.w;
        acc[4] += xv * b.x; acc[5] += xv * b.y; acc[6] += xv * b.z; acc[7] += xv * b.w;
    }
#pragma unroll
    for (int e = 0; e < 8; e++) {
#pragma unroll
        for (int off = 32; off > 0; off >>= 1)
            acc[e] += __shfl_xor(acc[e], off, 64);
    }
    if (lane == 0) {
        float lg[8];
#pragma unroll
        for (int e = 0; e < 8; e++) lg[e] = acc[e] + bg[e];
        int e1 = 0; float b1v = lg[0];
#pragma unroll
        for (int e = 1; e < 8; e++) if (lg[e] > b1v) { b1v = lg[e]; e1 = e; }
        int e2 = -1; float b2v = -3.0e38f;
#pragma unroll
        for (int e = 0; e < 8; e++) { if (e == e1) continue; if (lg[e] > b2v) { b2v = lg[e]; e2 = e; } }
        int b = tok >> 10;
        slot_e[2 * tok] = e1;
        slot_e[2 * tok + 1] = e2;
        atomicAdd(&grp_cnt[e1 * 8 + b], 1);
        atomicAdd(&grp_cnt[e2 * 8 + b], 1);
    }
}

// ---------- prefix sum + tile table ----------
__global__ void prefix_kernel(const int* __restrict__ grp_cnt, int* __restrict__ goff,
                              int* __restrict__ cursor, int2* __restrict__ tile_tab) {
    if (threadIdx.x != 0) return;
    int s = 0;
    for (int g = 0; g < NGRP; g++) { goff[g] = s; cursor[g] = s; s += grp_cnt[g]; }
    goff[NGRP] = s;
    int t = 0;
    for (int e = 0; e < 8; e++) {
        int cnt = goff[e * 8 + 8] - goff[e * 8];
        for (int m0 = 0; m0 < cnt; m0 += 128) tile_tab[t++] = make_int2(e, m0);
    }
    for (; t < MAXTILE; t++) tile_tab[t] = make_int2(-1, 0);
}

// ---------- gather x + noise into grouped bf16 rows ----------
__global__ void build_xg_kernel(const float* __restrict__ x, const float* __restrict__ noise,
                                const int* __restrict__ slot_e, int* __restrict__ cursor,
                                unsigned short* __restrict__ xg) {
    int wave = threadIdx.x >> 6;
    int lane = threadIdx.x & 63;
    int slot = blockIdx.x * 4 + wave;
    int e = slot_e[slot];
    int b = slot >> 11;
    int row = 0;
    if (lane == 0) row = atomicAdd(&cursor[e * 8 + b], 1);
    row = __shfl(row, 0, 64);
    int tok = slot >> 1;
    const float4* xr = reinterpret_cast<const float4*>(x + (size_t)tok * D);
    const float4* nr = reinterpret_cast<const float4*>(noise + (size_t)slot * D);
    ushort4* og = reinterpret_cast<ushort4*>(xg + (size_t)row * D);
    for (int i = lane; i < D / 4; i += 64) {
        float4 a = xr[i], n = nr[i];
        ushort4 o;
        o.x = f2bf(a.x + n.x); o.y = f2bf(a.y + n.y);
        o.z = f2bf(a.z + n.z); o.w = f2bf(a.w + n.w);
        og[i] = o;
    }
}

// ---------- W fp32 [e][k][n] -> bf16 blocked [e][k/8][n][8] ----------
// One block per (k-block, matrix): 2048 blocks, float4 reads / uint4 writes.
__global__ void wconv_kernel(const float* __restrict__ W1, const float* __restrict__ W2,
                             unsigned short* __restrict__ W1t, unsigned short* __restrict__ W2t) {
    int z = blockIdx.y;            // e*2 + mat
    int mat = z & 1, e = z >> 1;
    int kb = blockIdx.x;           // k-block: 8 consecutive k rows
    const float* src = (mat ? W2 : W1) + (size_t)e * D * D + (size_t)kb * 8 * D;
    unsigned short* dst = (mat ? W2t : W1t) + (size_t)e * D * D + (size_t)kb * (D * 8);
    int t = threadIdx.x;
    float4 v[8];
#pragma unroll
    for (int k = 0; k < 8; k++)
        v[k] = reinterpret_cast<const float4*>(src + (size_t)k * D)[t];
    const float* vf = reinterpret_cast<const float*>(v);   // vf[k*4+c]
#pragma unroll
    for (int c = 0; c < 4; c++) {
        unsigned int w[4];
#pragma unroll
        for (int j = 0; j < 4; j++) {
            unsigned short lo = f2bf(vf[(2 * j) * 4 + c]);
            unsigned short hi = f2bf(vf[(2 * j + 1) * 4 + c]);
            w[j] = (unsigned int)lo | ((unsigned int)hi << 16);
        }
        *reinterpret_cast<uint4*>(dst + (size_t)(t * 4 + c) * 8) = make_uint4(w[0], w[1], w[2], w[3]);
    }
}

// ---------- grouped GEMM: 128x64 tile, dbuf LDS, XCD-swizzled grid ----------
// A: row-major bf16 [m][1024].  Wt: blocked bf16 [e][k/8][n][8].
// MODE 0: H = gelu(A @ W^T + b1)   MODE 1: Y = A @ W^T + b2 + xg
// Grid: 2176 = 8 xcd-slots * 16 n-tiles * 17 m-groups. id%8 pins all 16
// n-tiles of one m-tile to the same XCD so the A-tile is fetched once per L2.
template <int MODE>
__global__ __launch_bounds__(256)
void gemm_kernel(const unsigned short* __restrict__ A,
                 const unsigned short* __restrict__ Wt,
                 const float* __restrict__ bias,
                 const unsigned short* __restrict__ xg,
                 const int2* __restrict__ tile_tab,
                 const int* __restrict__ goff,
                 unsigned short* __restrict__ Hout) {
    __shared__ unsigned short As[2][128 * 32];   // 2 x 8 KB
    __shared__ unsigned short Bs[2][64 * 32];    // 2 x 4 KB

    int id = blockIdx.x;
    int xcd = id & 7;
    int rem = id >> 3;
    int ntile = rem & 15;
    int t = xcd + 8 * (rem >> 4);      // 0..135
    int2 tt = tile_tab[t];
    int e = tt.x;
    if (e < 0) return;
    int m0 = tt.y;
    int rowBase = goff[e * 8];
    int cnt = goff[e * 8 + 8] - rowBase;
    int n0 = ntile * 64;

    int tid = threadIdx.x;
    int lane = tid & 63, wave = tid >> 6;
    int wm = wave >> 1, wn = wave & 1;
    int lr = lane & 15, quad = lane >> 4;
    int l2 = lane >> 2, l4 = lane & 3;

    int arow0 = min(m0 + (wave * 2 + 0) * 16 + l2, cnt - 1);
    int arow1 = min(m0 + (wave * 2 + 1) * 16 + l2, cnt - 1);
    const unsigned short* ap0 = A + ((size_t)(rowBase + arow0) << 10) + l4 * 8;
    const unsigned short* ap1 = A + ((size_t)(rowBase + arow1) << 10) + l4 * 8;
    const unsigned short* bp = Wt + (size_t)e * D * D
                               + (size_t)l4 * (D * 8)
                               + (size_t)(n0 + wave * 16 + l2) * 8;

    unsigned short* a_dst0[2] = { &As[0][(wave * 2 + 0) * 512 + lane * 8],
                                  &As[1][(wave * 2 + 0) * 512 + lane * 8] };
    unsigned short* a_dst1[2] = { &As[0][(wave * 2 + 1) * 512 + lane * 8],
                                  &As[1][(wave * 2 + 1) * 512 + lane * 8] };
    unsigned short* b_dst[2]  = { &Bs[0][wave * 512 + lane * 8],
                                  &Bs[1][wave * 512 + lane * 8] };

    const unsigned short* a_frag = &As[0][(wm * 64 + lr) * 32 + quad * 8];
    const unsigned short* b_frag = &Bs[0][(wn * 32 + lr) * 32 + quad * 8];

    floatx4 acc[4][2] = {};

    load_lds16(ap0, a_dst0[0]); load_lds16(ap1, a_dst1[0]); load_lds16(bp, b_dst[0]);
    ap0 += 32; ap1 += 32; bp += 4 * D * 8;

#pragma unroll 1
    for (int k0 = 0; k0 < D; k0 += 64) {
        __syncthreads();
        if (k0 + 32 < D) {
            load_lds16(ap0, a_dst0[1]); load_lds16(ap1, a_dst1[1]); load_lds16(bp, b_dst[1]);
            ap0 += 32; ap1 += 32; bp += 4 * D * 8;
        }
        {
            bf16x8 af[4], bfr[2];
#pragma unroll
            for (int i = 0; i < 4; i++)
                af[i] = *reinterpret_cast<const bf16x8*>(a_frag + i * 512);
#pragma unroll
            for (int j = 0; j < 2; j++)
                bfr[j] = *reinterpret_cast<const bf16x8*>(b_frag + j * 512);
#pragma unroll
            for (int i = 0; i < 4; i++)
#pragma unroll
                for (int j = 0; j < 2; j++)
                    acc[i][j] = __builtin_amdgcn_mfma_f32_16x16x32_bf16(af[i], bfr[j], acc[i][j], 0, 0, 0);
        }
        __syncthreads();
        if (k0 + 64 < D) {
            load_lds16(ap0, a_dst0[0]); load_lds16(ap1, a_dst1[0]); load_lds16(bp, b_dst[0]);
            ap0 += 32; ap1 += 32; bp += 4 * D * 8;
        }
        {
            bf16x8 af[4], bfr[2];
#pragma unroll
            for (int i = 0; i < 4; i++)
                af[i] = *reinterpret_cast<const bf16x8*>(a_frag + 4096 + i * 512);
#pragma unroll
            for (int j = 0; j < 2; j++)
                bfr[j] = *reinterpret_cast<const bf16x8*>(b_frag + 2048 + j * 512);
#pragma unroll
            for (int i = 0; i < 4; i++)
#pragma unroll
                for (int j = 0; j < 2; j++)
                    acc[i][j] = __builtin_amdgcn_mfma_f32_16x16x32_bf16(af[i], bfr[j], acc[i][j], 0, 0, 0);
        }
    }

#pragma unroll
    for (int i = 0; i < 4; i++) {
        int rowb = m0 + wm * 64 + i * 16 + quad * 4;
#pragma unroll
        for (int j = 0; j < 2; j++) {
            int col = n0 + wn * 32 + j * 16 + lr;
            float bia = bias[e * D + col];
#pragma unroll
            for (int r = 0; r < 4; r++) {
                int rr = rowb + r;
                if (rr < cnt) {
                    float v = acc[i][j][r] + bia;
                    size_t idx = (size_t)(rowBase + rr) * D + col;
                    if (MODE == 0) {
                        float g = 0.5f * v * (1.0f + erff(v * 0.70710678118654752f));
                        Hout[idx] = f2bf(g);
                    } else {
                        v += bf2f(xg[idx]);
                        Hout[idx] = f2bf(v);
                    }
                }
            }
        }
    }
}

// ---------- fused per-row LN + per-(e,b) segment sum (wave per row) ----------
__global__ void lnsum_kernel(const unsigned short* __restrict__ ybf,
                             const int* __restrict__ goff, float* __restrict__ S) {
    int grp = blockIdx.x, chunk = blockIdx.y;
    int r0 = goff[grp] + chunk * 64;
    int r1 = min(goff[grp + 1], r0 + 64);
    if (r0 >= r1) return;
    __shared__ float part[D];
    for (int i = threadIdx.x; i < D; i += 256) part[i] = 0.f;
    __syncthreads();

    int wave = threadIdx.x >> 6, lane = threadIdx.x & 63;
    float p[16] = {0.f};
    for (int r = r0 + wave; r < r1; r += 4) {
        const unsigned short* row = ybf + ((size_t)r << 10);
        float v[16];
        float s = 0.f, sq = 0.f;
#pragma unroll
        for (int c = 0; c < 4; c++) {
            ushort4 u = *reinterpret_cast<const ushort4*>(row + c * 256 + lane * 4);
            float a = bf2f(u.x), b = bf2f(u.y), cc = bf2f(u.z), d = bf2f(u.w);
            v[c * 4 + 0] = a; v[c * 4 + 1] = b; v[c * 4 + 2] = cc; v[c * 4 + 3] = d;
            s += a + b + cc + d;
            sq += a * a + b * b + cc * cc + d * d;
        }
#pragma unroll
        for (int off = 32; off > 0; off >>= 1) {
            s += __shfl_xor(s, off, 64);
            sq += __shfl_xor(sq, off, 64);
        }
        float m = s * (1.f / 1024.f);
        float rs = rsqrtf(sq * (1.f / 1024.f) - m * m + 1e-5f);
#pragma unroll
        for (int c = 0; c < 16; c++) p[c] += (v[c] - m) * rs;
    }
#pragma unroll
    for (int c = 0; c < 4; c++)
#pragma unroll
        for (int q = 0; q < 4; q++)
            atomicAdd(&part[c * 256 + lane * 4 + q], p[c * 4 + q]);
    __syncthreads();

    int e = grp >> 3, b = grp & 7;
    float* Sp = S + (size_t)(b * 8 + e) * D;
    for (int i = threadIdx.x; i < D; i += 256)
        atomicAdd(&Sp[i], part[i]);
}

// ---------- finalize: ln scale/bias + final group LN ----------
__global__ void finalize_kernel(const float* __restrict__ S, const int* __restrict__ goff,
                                const float* __restrict__ ln_g, const float* __restrict__ ln_b,
                                const float* __restrict__ gn_g, const float* __restrict__ gn_b,
                                float* __restrict__ out) {
    int be = blockIdx.x;           // b*8 + e
    int b = be >> 3, e = be & 7;
    int grp = e * 8 + b;
    float cnt = (float)(goff[grp + 1] - goff[grp]);
    int tid = threadIdx.x;
    __shared__ float red[8];
    float val[4];
    float s = 0.f, sq = 0.f;
#pragma unroll
    for (int c = 0; c < 4; c++) {
        int d = tid * 4 + c;
        float v = S[(size_t)be * D + d] * ln_g[e * D + d] + cnt * ln_b[e * D + d];
        val[c] = v; s += v; sq += v * v;
    }
#pragma unroll
    for (int off = 32; off > 0; off >>= 1) {
        s += __shfl_xor(s, off, 64);
        sq += __shfl_xor(sq, off, 64);
    }
    int wave = tid >> 6, lane = tid & 63;
    if (lane == 0) { red[wave] = s; red[4 + wave] = sq; }
    __syncthreads();
    float ts = red[0] + red[1] + red[2] + red[3];
    float tq = red[4] + red[5] + red[6] + red[7];
    float m = ts / 1024.f;
    float var = tq / 1024.f - m * m;
    float rstd = rsqrtf(var + 1e-5f);
#pragma unroll
    for (int c = 0; c < 4; c++) {
        int d = tid * 4 + c;
        out[(size_t)be * D + d] = (val[c] - m) * rstd * gn_g[d] + gn_b[d];
    }
}

extern "C" void kernel_launch(void* const* d_in, const int* in_sizes, int n_in,
                              void* d_out, int out_size, void* d_ws, size_t ws_size,
                              hipStream_t stream) {
    const float* x     = (const float*)d_in[0];
    const float* noise = (const float*)d_in[1];
    const float* Wg    = (const float*)d_in[2];
    const float* bg    = (const float*)d_in[3];
    const float* W1    = (const float*)d_in[4];
    const float* b1    = (const float*)d_in[5];
    const float* W2    = (const float*)d_in[6];
    const float* b2    = (const float*)d_in[7];
    const float* ln_g  = (const float*)d_in[8];
    const float* ln_b  = (const float*)d_in[9];
    const float* gn_g  = (const float*)d_in[10];
    const float* gn_b  = (const float*)d_in[11];
    float* out = (float*)d_out;

    char* ws = (char*)d_ws;
    size_t off = 0;
    unsigned short* xg   = (unsigned short*)(ws + off); off += (size_t)NSLOT * D * 2;   // 32 MB
    unsigned short* hb   = (unsigned short*)(ws + off); off += (size_t)NSLOT * D * 2;   // 32 MB
    unsigned short* ybf  = (unsigned short*)(ws + off); off += (size_t)NSLOT * D * 2;   // 32 MB
    unsigned short* W1t  = (unsigned short*)(ws + off); off += (size_t)8 * D * D * 2;   // 16 MB
    unsigned short* W2t  = (unsigned short*)(ws + off); off += (size_t)8 * D * D * 2;   // 16 MB
    int* slot_e          = (int*)(ws + off);            off += (size_t)NSLOT * 4;
    int* grp_cnt         = (int*)(ws + off);            off += 256;
    int* goff            = (int*)(ws + off);            off += 512;
    int* cursor          = (int*)(ws + off);            off += 256;
    int2* tile_tab       = (int2*)(ws + off);           off += MAXTILE * 8;
    float* S             = (float*)(ws + off);          off += (size_t)64 * D * 4;

    zero_kernel<<<256, 256, 0, stream>>>(grp_cnt, S);
    route_kernel<<<NTOK / 4, 256, 0, stream>>>(x, Wg, bg, slot_e, grp_cnt);
    prefix_kernel<<<1, 64, 0, stream>>>(grp_cnt, goff, cursor, tile_tab);
    wconv_kernel<<<dim3(128, 16), 256, 0, stream>>>(W1, W2, W1t, W2t);
    build_xg_kernel<<<NSLOT / 4, 256, 0, stream>>>(x, noise, slot_e, cursor, xg);
    gemm_kernel<0><<<dim3(2176), 256, 0, stream>>>(xg, W1t, b1, xg, tile_tab, goff, hb);
    gemm_kernel<1><<<dim3(2176), 256, 0, stream>>>(hb, W2t, b2, xg, tile_tab, goff, ybf);
    lnsum_kernel<<<dim3(64, 32), 256, 0, stream>>>(ybf, goff, S);
    finalize_kernel<<<64, 256, 0, stream>>>(S, goff, ln_g, ln_b, gn_g, gn_b, out);
}